// Round 10
// baseline (263.579 us; speedup 1.0000x reference)
//
#include <hip/hip_runtime.h>
#include <hip/hip_bf16.h>

typedef __bf16 bf16;
typedef __bf16 bf16x8 __attribute__((ext_vector_type(8)));
typedef float  f32x4  __attribute__((ext_vector_type(4)));

#define NEG_BIG (-1e30f)

#define AS1(p) ((const __attribute__((address_space(1))) void*)(p))
#define AS3(p) ((__attribute__((address_space(3))) void*)(p))

// async global->LDS, 16B/lane; dest = wave-uniform base + lane*16 (m104/m108)
__device__ __forceinline__ void stage16(const void* g, void* lds_uniform_base) {
    __builtin_amdgcn_global_load_lds(AS1(g), AS3(lds_uniform_base), 16, 0, 0);
}

__device__ __forceinline__ bf16x8 cvt8(const float* __restrict__ p) {
    bf16x8 r;
#pragma unroll
    for (int i = 0; i < 8; ++i) r[i] = (bf16)p[i];
    return r;
}

// ---------------------------------------------------------------------------
// f32->bf16: x -> xb (ws), Wq/Wk/Wv -> wb (d_out scratch). (R7-proven.)
// ---------------------------------------------------------------------------
__global__ __launch_bounds__(256) void conv_all(
    const float* __restrict__ x,  const float* __restrict__ wq,
    const float* __restrict__ wk, const float* __restrict__ wv,
    bf16* __restrict__ xb, bf16* __restrict__ wb)
{
    const int blk = blockIdx.x;
    const float* src; bf16* dst; size_t off;
    if (blk < 2048)      { src = x;  dst = xb;           off = (size_t)blk * 2048; }
    else if (blk < 2560) { src = wq; dst = wb;           off = (size_t)(blk - 2048) * 2048; }
    else if (blk < 3072) { src = wk; dst = wb + 1048576; off = (size_t)(blk - 2560) * 2048; }
    else                 { src = wv; dst = wb + 2097152; off = (size_t)(blk - 3072) * 2048; }
    const size_t i = off + (size_t)threadIdx.x * 8;
    *(bf16x8*)(dst + i) = cvt8(src + i);
}

// ---------------------------------------------------------------------------
// Fused QKV projection, all-bf16 (R7-proven). y = xb @ Wb.T + b.
// ---------------------------------------------------------------------------
__global__ __launch_bounds__(256) void qkv_gemm(
    const bf16* __restrict__ Xb, const bf16* __restrict__ Wb,
    const float* __restrict__ bq, const float* __restrict__ bk, const float* __restrict__ bv,
    bf16* __restrict__ qo, bf16* __restrict__ ko, bf16* __restrict__ vo)
{
    __shared__ alignas(16) bf16 As[128 * 32];
    __shared__ alignas(16) bf16 Bs[128 * 32];

    const int t    = threadIdx.x;
    const int lane = t & 63, w = t >> 6;
    const int quad = lane >> 4, col = lane & 15;
    const int nt = blockIdx.x;            // 0..23
    const int mt = blockIdx.y;            // 0..31
    const int region = nt >> 3;           // 0=q 1=k 2=v
    const int n0 = (nt & 7) * 128;
    const int m0 = mt * 128;
    const int K  = 1024;

    const bf16*  W    = Wb + (size_t)region * 1048576;
    const float* bias = region == 0 ? bq : (region == 1 ? bk : bv);
    bf16*        out  = region == 0 ? qo : (region == 1 ? ko : vo);
    const float scale = region == 0 ? 0.125f : 1.0f;

    const int wm = (w >> 1) * 64, wn = (w & 1) * 64;
    f32x4 acc[4][4] = {};

    for (int k0 = 0; k0 < K; k0 += 32) {
        __syncthreads();
#pragma unroll
        for (int i = 0; i < 2; ++i) {
            int c = i * 256 + t;
            stage16(Xb + (size_t)(m0 + (c >> 2)) * K + k0 + (c & 3) * 8,
                    As + (i * 256 + w * 64) * 8);
        }
#pragma unroll
        for (int i = 0; i < 2; ++i) {
            int c = i * 256 + t;
            stage16(W + (size_t)(n0 + (c >> 2)) * K + k0 + (c & 3) * 8,
                    Bs + (i * 256 + w * 64) * 8);
        }
        __syncthreads();

        bf16x8 a[4], b[4];
#pragma unroll
        for (int i = 0; i < 4; ++i)
            a[i] = *(const bf16x8*)(As + (wm + i * 16 + col) * 32 + quad * 8);
#pragma unroll
        for (int j = 0; j < 4; ++j)
            b[j] = *(const bf16x8*)(Bs + (wn + j * 16 + col) * 32 + quad * 8);
#pragma unroll
        for (int i = 0; i < 4; ++i)
#pragma unroll
            for (int j = 0; j < 4; ++j)
                acc[i][j] = __builtin_amdgcn_mfma_f32_16x16x32_bf16(a[i], b[j], acc[i][j], 0, 0, 0);
    }

#pragma unroll
    for (int i = 0; i < 4; ++i) {
        const int mbase = m0 + wm + i * 16 + quad * 4;
#pragma unroll
        for (int j = 0; j < 4; ++j) {
            const int n = n0 + wn + j * 16 + col;
            const float bb = bias[n];
            const int h = n >> 6, d = n & 63;
#pragma unroll
            for (int r = 0; r < 4; ++r) {
                const int m  = mbase + r;
                const int b_ = m >> 11, s = m & 2047;
                out[(((size_t)(b_ * 16 + h)) * 2048 + s) * 64 + d] =
                    (bf16)((acc[i][j][r] + bb) * scale);
            }
        }
    }
}

// ---------------------------------------------------------------------------
// Flash attention — R7-proven dataflow (LDS K staging, 3 barriers, online
// softmax, Ks∪Ps union, Vt transposed), retiled for load balance:
//   Q-tile 64 rows, 2 waves/block (32 rows each), grid = 32 qt x 32 bh = 1024
//   blocks (4/CU; R7 had 512 coarse blocks = 1.8x tail imbalance).
// Only the thread->element index maps changed (128 threads); kv loop bound
// becomes kvmax = qt>>1. All inner machinery verbatim.
// ---------------------------------------------------------------------------
__global__ __launch_bounds__(128) void attn_kernel(
    const bf16* __restrict__ Q, const bf16* __restrict__ Kg,
    const bf16* __restrict__ Vg, bf16* __restrict__ O)
{
    const int t    = threadIdx.x;          // 0..127
    const int lane = t & 63, w = t >> 6;   // w in {0,1}
    const int quad = lane >> 4, col = lane & 15;
    const int bh = blockIdx.x & 31;
    const int qt = 31 - (blockIdx.x >> 5); // 0..31, biggest tiles first
    const int b  = bh >> 4, h = bh & 15;
    const int q0 = qt * 64;
    const float nslope = -exp2f(-0.5f * (float)(h + 1));

    const bf16* qp = Q  + (size_t)bh * 2048 * 64;
    const bf16* kp = Kg + (size_t)bh * 2048 * 64;
    const bf16* vp = Vg + (size_t)bh * 2048 * 64;

    __shared__ alignas(16) bf16 KP[9216];    // Ks 128x72 (9216) ∪ Ps 2x[32][136] (8704)
    __shared__ alignas(16) bf16 Vt[64 * 136];
    bf16* Ks = KP;
    bf16* Pw = KP + w * (32 * 136);

    bf16x8 qa[2][2];
#pragma unroll
    for (int mi = 0; mi < 2; ++mi)
#pragma unroll
        for (int ks = 0; ks < 2; ++ks)
            qa[mi][ks] = *(const bf16x8*)(qp + (size_t)(q0 + w * 32 + mi * 16 + col) * 64
                                          + ks * 32 + quad * 8);

    float mrow[2][4], lrow[2][4];
    f32x4 of[2][4] = {};
#pragma unroll
    for (int mi = 0; mi < 2; ++mi)
#pragma unroll
        for (int r = 0; r < 4; ++r) { mrow[mi][r] = NEG_BIG; lrow[mi][r] = 0.f; }

    const int kvmax = qt >> 1;
    for (int kvt = 0; kvt <= kvmax; ++kvt) {
        const int kv0 = kvt * 128;

        bf16x8 kx[8], va[4], vb_[4];
#pragma unroll
        for (int i = 0; i < 8; ++i) {          // K tile: 1024 chunks / 128 thr
            int c = i * 128 + t;
            kx[i] = *(const bf16x8*)(kp + (size_t)(kv0 + (c >> 3)) * 64 + (c & 7) * 8);
        }
#pragma unroll
        for (int i = 0; i < 4; ++i) {          // V tile: 512 pair-chunks / 128 thr
            int c = i * 128 + t;
            va[i]  = *(const bf16x8*)(vp + (size_t)(kv0 + (c >> 3) * 2)     * 64 + (c & 7) * 8);
            vb_[i] = *(const bf16x8*)(vp + (size_t)(kv0 + (c >> 3) * 2 + 1) * 64 + (c & 7) * 8);
        }
        __syncthreads();   // BARRIER1: all waves done with prev KP(Pw)/Vt reads
#pragma unroll
        for (int i = 0; i < 8; ++i) {
            int c = i * 128 + t;
            *(bf16x8*)(Ks + (c >> 3) * 72 + (c & 7) * 8) = kx[i];
        }
#pragma unroll
        for (int i = 0; i < 4; ++i) {
            int c = i * 128 + t;
            int kvp = c >> 3, dc = (c & 7) * 8;
#pragma unroll
            for (int e = 0; e < 8; ++e) {
                Vt[(dc + e) * 136 + kvp * 2]     = va[i][e];
                Vt[(dc + e) * 136 + kvp * 2 + 1] = vb_[i][e];
            }
        }
        __syncthreads();   // BARRIER2: Ks/Vt visible

        // S = Q K^T
        f32x4 sc[2][8];
#pragma unroll
        for (int nj = 0; nj < 8; ++nj) {
            bf16x8 k0f = *(const bf16x8*)(Ks + (nj * 16 + col) * 72 + quad * 8);
            bf16x8 k1f = *(const bf16x8*)(Ks + (nj * 16 + col) * 72 + 32 + quad * 8);
#pragma unroll
            for (int mi = 0; mi < 2; ++mi) {
                f32x4 z = {};
                z = __builtin_amdgcn_mfma_f32_16x16x32_bf16(qa[mi][0], k0f, z, 0, 0, 0);
                z = __builtin_amdgcn_mfma_f32_16x16x32_bf16(qa[mi][1], k1f, z, 0, 0, 0);
                sc[mi][nj] = z;
            }
        }

        const bool diag = (kvt == kvmax);
#pragma unroll
        for (int mi = 0; mi < 2; ++mi) {
#pragma unroll
            for (int r = 0; r < 4; ++r) {
                const int gi = q0 + w * 32 + mi * 16 + quad * 4 + r;
                float mx = NEG_BIG;
#pragma unroll
                for (int nj = 0; nj < 8; ++nj) {
                    const int gj = kv0 + nj * 16 + col;
                    float val = sc[mi][nj][r] + nslope * (float)(gi - gj);
                    if (diag && gj > gi) val = NEG_BIG;
                    sc[mi][nj][r] = val;
                    mx = fmaxf(mx, val);
                }
#pragma unroll
                for (int off = 1; off < 16; off <<= 1)
                    mx = fmaxf(mx, __shfl_xor(mx, off, 16));
                const float mo = mrow[mi][r];
                const float mn = fmaxf(mo, mx);
                const float alpha = __expf(mo - mn);
                float rs = 0.f;
#pragma unroll
                for (int nj = 0; nj < 8; ++nj) {
                    float p = __expf(sc[mi][nj][r] - mn);
                    sc[mi][nj][r] = p;
                    rs += p;
                }
#pragma unroll
                for (int off = 1; off < 16; off <<= 1)
                    rs += __shfl_xor(rs, off, 16);
                mrow[mi][r] = mn;
                lrow[mi][r] = lrow[mi][r] * alpha + rs;
#pragma unroll
                for (int jd = 0; jd < 4; ++jd) of[mi][jd][r] *= alpha;
            }
        }

        __syncthreads();   // BARRIER3: all waves done reading Ks before P overwrite

        // P: C/D -> A-operand layout via per-wave LDS region (aliases Ks)
#pragma unroll
        for (int mi = 0; mi < 2; ++mi)
#pragma unroll
            for (int nj = 0; nj < 8; ++nj)
#pragma unroll
                for (int r = 0; r < 4; ++r)
                    Pw[(mi * 16 + quad * 4 + r) * 136 + nj * 16 + col] = (bf16)sc[mi][nj][r];

        // O += P V
#pragma unroll
        for (int kk = 0; kk < 4; ++kk) {
            bf16x8 pa0 = *(const bf16x8*)(Pw + (col)      * 136 + kk * 32 + quad * 8);
            bf16x8 pa1 = *(const bf16x8*)(Pw + (16 + col) * 136 + kk * 32 + quad * 8);
#pragma unroll
            for (int jd = 0; jd < 4; ++jd) {
                bf16x8 vbf = *(const bf16x8*)(Vt + (jd * 16 + col) * 136 + kk * 32 + quad * 8);
                of[0][jd] = __builtin_amdgcn_mfma_f32_16x16x32_bf16(pa0, vbf, of[0][jd], 0, 0, 0);
                of[1][jd] = __builtin_amdgcn_mfma_f32_16x16x32_bf16(pa1, vbf, of[1][jd], 0, 0, 0);
            }
        }
    }

    // normalize + write attn output (bf16) to [B,S,E]
#pragma unroll
    for (int mi = 0; mi < 2; ++mi)
#pragma unroll
        for (int r = 0; r < 4; ++r) {
            const int s = q0 + w * 32 + mi * 16 + quad * 4 + r;
            const float inv_l = 1.f / lrow[mi][r];
#pragma unroll
            for (int jd = 0; jd < 4; ++jd) {
                const int e = h * 64 + jd * 16 + col;
                O[((size_t)(b * 2048 + s)) * 1024 + e] = (bf16)(of[mi][jd][r] * inv_l);
            }
        }
}

// ---------------------------------------------------------------------------
// Output projection (R7-proven): A bf16 via stage16; Wo f32 via cvt8.
// ---------------------------------------------------------------------------
__global__ __launch_bounds__(256) void out_gemm(
    const bf16* __restrict__ A, const float* __restrict__ W,
    const float* __restrict__ bias, float* __restrict__ out)
{
    __shared__ alignas(16) bf16 As[128 * 32];
    __shared__ alignas(16) bf16 Bs[128 * 32];

    const int t    = threadIdx.x;
    const int lane = t & 63, w = t >> 6;
    const int quad = lane >> 4, col = lane & 15;
    const int n0 = blockIdx.x * 128;
    const int m0 = blockIdx.y * 128;
    const int K  = 1024;
    const int wm = (w >> 1) * 64, wn = (w & 1) * 64;
    const int r0 = t >> 2, c8 = (t & 3) * 8;
    f32x4 acc[4][4] = {};

    for (int k0 = 0; k0 < K; k0 += 32) {
        bf16x8 bx0 = cvt8(W + (size_t)(n0 + r0)      * K + k0 + c8);
        bf16x8 bx1 = cvt8(W + (size_t)(n0 + 64 + r0) * K + k0 + c8);
        __syncthreads();
#pragma unroll
        for (int i = 0; i < 2; ++i) {
            int c = i * 256 + t;
            stage16(A + (size_t)(m0 + (c >> 2)) * K + k0 + (c & 3) * 8,
                    As + (i * 256 + w * 64) * 8);
        }
        *(bf16x8*)(Bs + r0 * 32 + c8)        = bx0;
        *(bf16x8*)(Bs + (64 + r0) * 32 + c8) = bx1;
        __syncthreads();

        bf16x8 a[4], b[4];
#pragma unroll
        for (int i = 0; i < 4; ++i)
            a[i] = *(const bf16x8*)(As + (wm + i * 16 + col) * 32 + quad * 8);
#pragma unroll
        for (int j = 0; j < 4; ++j)
            b[j] = *(const bf16x8*)(Bs + (wn + j * 16 + col) * 32 + quad * 8);
#pragma unroll
        for (int i = 0; i < 4; ++i)
#pragma unroll
            for (int j = 0; j < 4; ++j)
                acc[i][j] = __builtin_amdgcn_mfma_f32_16x16x32_bf16(a[i], b[j], acc[i][j], 0, 0, 0);
    }

#pragma unroll
    for (int i = 0; i < 4; ++i) {
        const int mbase = m0 + wm + i * 16 + quad * 4;
#pragma unroll
        for (int j = 0; j < 4; ++j) {
            const int n = n0 + wn + j * 16 + col;
            const float bb = bias[n];
#pragma unroll
            for (int r = 0; r < 4; ++r)
                out[(size_t)(mbase + r) * 1024 + n] = acc[i][j][r] + bb;
        }
    }
}

extern "C" void kernel_launch(void* const* d_in, const int* in_sizes, int n_in,
                              void* d_out, int out_size, void* d_ws, size_t ws_size,
                              hipStream_t stream) {
    const float* x  = (const float*)d_in[0];
    const float* Wq = (const float*)d_in[1];
    const float* bq = (const float*)d_in[2];
    const float* Wk = (const float*)d_in[3];
    const float* bk = (const float*)d_in[4];
    const float* Wv = (const float*)d_in[5];
    const float* bv = (const float*)d_in[6];
    const float* Wo = (const float*)d_in[7];
    const float* bo = (const float*)d_in[8];
    float* out = (float*)d_out;

    // ws (32 MB, proven): [xb | q | k | v] bf16; attn output aliases xb.
    bf16* xb  = (bf16*)d_ws;
    bf16* qws = xb  + 4194304;
    bf16* kws = qws + 4194304;
    bf16* vws = kws + 4194304;
    bf16* aws = xb;

    // d_out scratch: bf16 Wq|Wk|Wv (6 MB); dead before out_gemm writes.
    bf16* wb = (bf16*)d_out;

    conv_all<<<dim3(3584), 256, 0, stream>>>(x, Wq, Wk, Wv, xb, wb);
    qkv_gemm<<<dim3(24, 32), 256, 0, stream>>>(xb, wb, bq, bk, bv, qws, kws, vws);
    attn_kernel<<<dim3(1024), 128, 0, stream>>>(qws, kws, vws, aws);
    out_gemm<<<dim3(8, 32), 256, 0, stream>>>(aws, Wo, bo, out);
}

// Round 11
// 244.157 us; speedup vs baseline: 1.0795x; 1.0795x over previous
//
#include <hip/hip_runtime.h>
#include <hip/hip_bf16.h>

typedef __bf16 bf16;
typedef __bf16 bf16x8 __attribute__((ext_vector_type(8)));
typedef float  f32x4  __attribute__((ext_vector_type(4)));

#define NEG_BIG (-1e30f)

#define AS1(p) ((const __attribute__((address_space(1))) void*)(p))
#define AS3(p) ((__attribute__((address_space(3))) void*)(p))

// async global->LDS, 16B/lane; dest = wave-uniform base + lane*16 (m104/m108)
__device__ __forceinline__ void stage16(const void* g, void* lds_uniform_base) {
    __builtin_amdgcn_global_load_lds(AS1(g), AS3(lds_uniform_base), 16, 0, 0);
}

__device__ __forceinline__ bf16x8 cvt8(const float* __restrict__ p) {
    bf16x8 r;
#pragma unroll
    for (int i = 0; i < 8; ++i) r[i] = (bf16)p[i];
    return r;
}

// ---------------------------------------------------------------------------
// f32->bf16: x -> xb (ws), Wq/Wk/Wv -> wb (d_out scratch). (R7-proven.)
// ---------------------------------------------------------------------------
__global__ __launch_bounds__(256) void conv_all(
    const float* __restrict__ x,  const float* __restrict__ wq,
    const float* __restrict__ wk, const float* __restrict__ wv,
    bf16* __restrict__ xb, bf16* __restrict__ wb)
{
    const int blk = blockIdx.x;
    const float* src; bf16* dst; size_t off;
    if (blk < 2048)      { src = x;  dst = xb;           off = (size_t)blk * 2048; }
    else if (blk < 2560) { src = wq; dst = wb;           off = (size_t)(blk - 2048) * 2048; }
    else if (blk < 3072) { src = wk; dst = wb + 1048576; off = (size_t)(blk - 2560) * 2048; }
    else                 { src = wv; dst = wb + 2097152; off = (size_t)(blk - 3072) * 2048; }
    const size_t i = off + (size_t)threadIdx.x * 8;
    *(bf16x8*)(dst + i) = cvt8(src + i);
}

// ---------------------------------------------------------------------------
// Fused QKV projection, all-bf16 (R7-proven). y = xb @ Wb.T + b.
// ---------------------------------------------------------------------------
__global__ __launch_bounds__(256) void qkv_gemm(
    const bf16* __restrict__ Xb, const bf16* __restrict__ Wb,
    const float* __restrict__ bq, const float* __restrict__ bk, const float* __restrict__ bv,
    bf16* __restrict__ qo, bf16* __restrict__ ko, bf16* __restrict__ vo)
{
    __shared__ alignas(16) bf16 As[128 * 32];
    __shared__ alignas(16) bf16 Bs[128 * 32];

    const int t    = threadIdx.x;
    const int lane = t & 63, w = t >> 6;
    const int quad = lane >> 4, col = lane & 15;
    const int nt = blockIdx.x;            // 0..23
    const int mt = blockIdx.y;            // 0..31
    const int region = nt >> 3;           // 0=q 1=k 2=v
    const int n0 = (nt & 7) * 128;
    const int m0 = mt * 128;
    const int K  = 1024;

    const bf16*  W    = Wb + (size_t)region * 1048576;
    const float* bias = region == 0 ? bq : (region == 1 ? bk : bv);
    bf16*        out  = region == 0 ? qo : (region == 1 ? ko : vo);
    const float scale = region == 0 ? 0.125f : 1.0f;

    const int wm = (w >> 1) * 64, wn = (w & 1) * 64;
    f32x4 acc[4][4] = {};

    for (int k0 = 0; k0 < K; k0 += 32) {
        __syncthreads();
#pragma unroll
        for (int i = 0; i < 2; ++i) {
            int c = i * 256 + t;
            stage16(Xb + (size_t)(m0 + (c >> 2)) * K + k0 + (c & 3) * 8,
                    As + (i * 256 + w * 64) * 8);
        }
#pragma unroll
        for (int i = 0; i < 2; ++i) {
            int c = i * 256 + t;
            stage16(W + (size_t)(n0 + (c >> 2)) * K + k0 + (c & 3) * 8,
                    Bs + (i * 256 + w * 64) * 8);
        }
        __syncthreads();

        bf16x8 a[4], b[4];
#pragma unroll
        for (int i = 0; i < 4; ++i)
            a[i] = *(const bf16x8*)(As + (wm + i * 16 + col) * 32 + quad * 8);
#pragma unroll
        for (int j = 0; j < 4; ++j)
            b[j] = *(const bf16x8*)(Bs + (wn + j * 16 + col) * 32 + quad * 8);
#pragma unroll
        for (int i = 0; i < 4; ++i)
#pragma unroll
            for (int j = 0; j < 4; ++j)
                acc[i][j] = __builtin_amdgcn_mfma_f32_16x16x32_bf16(a[i], b[j], acc[i][j], 0, 0, 0);
    }

#pragma unroll
    for (int i = 0; i < 4; ++i) {
        const int mbase = m0 + wm + i * 16 + quad * 4;
#pragma unroll
        for (int j = 0; j < 4; ++j) {
            const int n = n0 + wn + j * 16 + col;
            const float bb = bias[n];
            const int h = n >> 6, d = n & 63;
#pragma unroll
            for (int r = 0; r < 4; ++r) {
                const int m  = mbase + r;
                const int b_ = m >> 11, s = m & 2047;
                out[(((size_t)(b_ * 16 + h)) * 2048 + s) * 64 + d] =
                    (bf16)((acc[i][j][r] + bb) * scale);
            }
        }
    }
}

// ---------------------------------------------------------------------------
// Flash attention — R7-proven structure (128-row Q tile, 4 waves, LDS K
// staging, Ks∪Ps union, 3 barriers, online softmax) + ONE delta: global
// K/V loads for tile t+1 are issued right after BARRIER2 of tile t, so
// their latency overlaps the whole compute phase instead of the loop top.
// ---------------------------------------------------------------------------
__global__ __launch_bounds__(256) void attn_kernel(
    const bf16* __restrict__ Q, const bf16* __restrict__ Kg,
    const bf16* __restrict__ Vg, bf16* __restrict__ O)
{
    const int t    = threadIdx.x;
    const int lane = t & 63, w = t >> 6;
    const int quad = lane >> 4, col = lane & 15;
    const int bh = blockIdx.x & 31;
    const int qt = 15 - (blockIdx.x >> 5);    // biggest tiles dispatched first
    const int b  = bh >> 4, h = bh & 15;
    const int q0 = qt * 128;
    const float nslope = -exp2f(-0.5f * (float)(h + 1));

    const bf16* qp = Q  + (size_t)bh * 2048 * 64;
    const bf16* kp = Kg + (size_t)bh * 2048 * 64;
    const bf16* vp = Vg + (size_t)bh * 2048 * 64;

    __shared__ alignas(16) bf16 KP[4 * 32 * 136];   // Ks (9216) ∪ Ps (17408)
    __shared__ alignas(16) bf16 Vt[64 * 136];
    bf16* Ks = KP;
    bf16* Pw = KP + w * (32 * 136);

    bf16x8 qa[2][2];
#pragma unroll
    for (int mi = 0; mi < 2; ++mi)
#pragma unroll
        for (int ks = 0; ks < 2; ++ks)
            qa[mi][ks] = *(const bf16x8*)(qp + (size_t)(q0 + w * 32 + mi * 16 + col) * 64
                                          + ks * 32 + quad * 8);

    float mrow[2][4], lrow[2][4];
    f32x4 of[2][4] = {};
#pragma unroll
    for (int mi = 0; mi < 2; ++mi)
#pragma unroll
        for (int r = 0; r < 4; ++r) { mrow[mi][r] = NEG_BIG; lrow[mi][r] = 0.f; }

    // preload tile 0 K/V into registers (same index maps as R7)
    bf16x8 kx[4], va[2], vb_[2];
#pragma unroll
    for (int i = 0; i < 4; ++i) {
        int c = i * 256 + t;
        kx[i] = *(const bf16x8*)(kp + (size_t)((c >> 3)) * 64 + (c & 7) * 8);
    }
#pragma unroll
    for (int i = 0; i < 2; ++i) {
        int c = i * 256 + t;
        va[i]  = *(const bf16x8*)(vp + (size_t)((c >> 3) * 2)     * 64 + (c & 7) * 8);
        vb_[i] = *(const bf16x8*)(vp + (size_t)((c >> 3) * 2 + 1) * 64 + (c & 7) * 8);
    }

    for (int kvt = 0; kvt <= qt; ++kvt) {
        __syncthreads();   // BARRIER1: all waves done with prev KP(Pw)/Vt reads
#pragma unroll
        for (int i = 0; i < 4; ++i) {
            int c = i * 256 + t;
            *(bf16x8*)(Ks + (c >> 3) * 72 + (c & 7) * 8) = kx[i];
        }
#pragma unroll
        for (int i = 0; i < 2; ++i) {
            int c = i * 256 + t;
            int kvp = c >> 3, dc = (c & 7) * 8;
#pragma unroll
            for (int e = 0; e < 8; ++e) {
                Vt[(dc + e) * 136 + kvp * 2]     = va[i][e];
                Vt[(dc + e) * 136 + kvp * 2 + 1] = vb_[i][e];
            }
        }
        __syncthreads();   // BARRIER2: Ks/Vt visible

        // issue next tile's global loads NOW — latency hides under compute
        if (kvt < qt) {
            const int nv0 = (kvt + 1) * 128;
#pragma unroll
            for (int i = 0; i < 4; ++i) {
                int c = i * 256 + t;
                kx[i] = *(const bf16x8*)(kp + (size_t)(nv0 + (c >> 3)) * 64 + (c & 7) * 8);
            }
#pragma unroll
            for (int i = 0; i < 2; ++i) {
                int c = i * 256 + t;
                va[i]  = *(const bf16x8*)(vp + (size_t)(nv0 + (c >> 3) * 2)     * 64 + (c & 7) * 8);
                vb_[i] = *(const bf16x8*)(vp + (size_t)(nv0 + (c >> 3) * 2 + 1) * 64 + (c & 7) * 8);
            }
        }

        const int kv0 = kvt * 128;

        // S = Q K^T
        f32x4 sc[2][8];
#pragma unroll
        for (int nj = 0; nj < 8; ++nj) {
            bf16x8 k0f = *(const bf16x8*)(Ks + (nj * 16 + col) * 72 + quad * 8);
            bf16x8 k1f = *(const bf16x8*)(Ks + (nj * 16 + col) * 72 + 32 + quad * 8);
#pragma unroll
            for (int mi = 0; mi < 2; ++mi) {
                f32x4 z = {};
                z = __builtin_amdgcn_mfma_f32_16x16x32_bf16(qa[mi][0], k0f, z, 0, 0, 0);
                z = __builtin_amdgcn_mfma_f32_16x16x32_bf16(qa[mi][1], k1f, z, 0, 0, 0);
                sc[mi][nj] = z;
            }
        }

        const bool diag = (kvt == qt);
#pragma unroll
        for (int mi = 0; mi < 2; ++mi) {
#pragma unroll
            for (int r = 0; r < 4; ++r) {
                const int gi = q0 + w * 32 + mi * 16 + quad * 4 + r;
                float mx = NEG_BIG;
#pragma unroll
                for (int nj = 0; nj < 8; ++nj) {
                    const int gj = kv0 + nj * 16 + col;
                    float val = sc[mi][nj][r] + nslope * (float)(gi - gj);
                    if (diag && gj > gi) val = NEG_BIG;
                    sc[mi][nj][r] = val;
                    mx = fmaxf(mx, val);
                }
#pragma unroll
                for (int off = 1; off < 16; off <<= 1)
                    mx = fmaxf(mx, __shfl_xor(mx, off, 16));
                const float mo = mrow[mi][r];
                const float mn = fmaxf(mo, mx);
                const float alpha = __expf(mo - mn);
                float rs = 0.f;
#pragma unroll
                for (int nj = 0; nj < 8; ++nj) {
                    float p = __expf(sc[mi][nj][r] - mn);
                    sc[mi][nj][r] = p;
                    rs += p;
                }
#pragma unroll
                for (int off = 1; off < 16; off <<= 1)
                    rs += __shfl_xor(rs, off, 16);
                mrow[mi][r] = mn;
                lrow[mi][r] = lrow[mi][r] * alpha + rs;
#pragma unroll
                for (int jd = 0; jd < 4; ++jd) of[mi][jd][r] *= alpha;
            }
        }

        __syncthreads();   // BARRIER3: all waves done reading Ks before P overwrite

        // P: C/D -> A-operand layout via per-wave LDS region (aliases Ks)
#pragma unroll
        for (int mi = 0; mi < 2; ++mi)
#pragma unroll
            for (int nj = 0; nj < 8; ++nj)
#pragma unroll
                for (int r = 0; r < 4; ++r)
                    Pw[(mi * 16 + quad * 4 + r) * 136 + nj * 16 + col] = (bf16)sc[mi][nj][r];

        // O += P V
#pragma unroll
        for (int kk = 0; kk < 4; ++kk) {
            bf16x8 pa0 = *(const bf16x8*)(Pw + (col)      * 136 + kk * 32 + quad * 8);
            bf16x8 pa1 = *(const bf16x8*)(Pw + (16 + col) * 136 + kk * 32 + quad * 8);
#pragma unroll
            for (int jd = 0; jd < 4; ++jd) {
                bf16x8 vbf = *(const bf16x8*)(Vt + (jd * 16 + col) * 136 + kk * 32 + quad * 8);
                of[0][jd] = __builtin_amdgcn_mfma_f32_16x16x32_bf16(pa0, vbf, of[0][jd], 0, 0, 0);
                of[1][jd] = __builtin_amdgcn_mfma_f32_16x16x32_bf16(pa1, vbf, of[1][jd], 0, 0, 0);
            }
        }
    }

    // normalize + write attn output (bf16) to [B,S,E]
#pragma unroll
    for (int mi = 0; mi < 2; ++mi)
#pragma unroll
        for (int r = 0; r < 4; ++r) {
            const int s = q0 + w * 32 + mi * 16 + quad * 4 + r;
            const float inv_l = 1.f / lrow[mi][r];
#pragma unroll
            for (int jd = 0; jd < 4; ++jd) {
                const int e = h * 64 + jd * 16 + col;
                O[((size_t)(b * 2048 + s)) * 1024 + e] = (bf16)(of[mi][jd][r] * inv_l);
            }
        }
}

// ---------------------------------------------------------------------------
// Output projection (R7-proven): A bf16 via stage16; Wo f32 via cvt8.
// ---------------------------------------------------------------------------
__global__ __launch_bounds__(256) void out_gemm(
    const bf16* __restrict__ A, const float* __restrict__ W,
    const float* __restrict__ bias, float* __restrict__ out)
{
    __shared__ alignas(16) bf16 As[128 * 32];
    __shared__ alignas(16) bf16 Bs[128 * 32];

    const int t    = threadIdx.x;
    const int lane = t & 63, w = t >> 6;
    const int quad = lane >> 4, col = lane & 15;
    const int n0 = blockIdx.x * 128;
    const int m0 = blockIdx.y * 128;
    const int K  = 1024;
    const int wm = (w >> 1) * 64, wn = (w & 1) * 64;
    const int r0 = t >> 2, c8 = (t & 3) * 8;
    f32x4 acc[4][4] = {};

    for (int k0 = 0; k0 < K; k0 += 32) {
        bf16x8 bx0 = cvt8(W + (size_t)(n0 + r0)      * K + k0 + c8);
        bf16x8 bx1 = cvt8(W + (size_t)(n0 + 64 + r0) * K + k0 + c8);
        __syncthreads();
#pragma unroll
        for (int i = 0; i < 2; ++i) {
            int c = i * 256 + t;
            stage16(A + (size_t)(m0 + (c >> 2)) * K + k0 + (c & 3) * 8,
                    As + (i * 256 + w * 64) * 8);
        }
        *(bf16x8*)(Bs + r0 * 32 + c8)        = bx0;
        *(bf16x8*)(Bs + (64 + r0) * 32 + c8) = bx1;
        __syncthreads();

        bf16x8 a[4], b[4];
#pragma unroll
        for (int i = 0; i < 4; ++i)
            a[i] = *(const bf16x8*)(As + (wm + i * 16 + col) * 32 + quad * 8);
#pragma unroll
        for (int j = 0; j < 4; ++j)
            b[j] = *(const bf16x8*)(Bs + (wn + j * 16 + col) * 32 + quad * 8);
#pragma unroll
        for (int i = 0; i < 4; ++i)
#pragma unroll
            for (int j = 0; j < 4; ++j)
                acc[i][j] = __builtin_amdgcn_mfma_f32_16x16x32_bf16(a[i], b[j], acc[i][j], 0, 0, 0);
    }

#pragma unroll
    for (int i = 0; i < 4; ++i) {
        const int mbase = m0 + wm + i * 16 + quad * 4;
#pragma unroll
        for (int j = 0; j < 4; ++j) {
            const int n = n0 + wn + j * 16 + col;
            const float bb = bias[n];
#pragma unroll
            for (int r = 0; r < 4; ++r)
                out[(size_t)(mbase + r) * 1024 + n] = acc[i][j][r] + bb;
        }
    }
}

extern "C" void kernel_launch(void* const* d_in, const int* in_sizes, int n_in,
                              void* d_out, int out_size, void* d_ws, size_t ws_size,
                              hipStream_t stream) {
    const float* x  = (const float*)d_in[0];
    const float* Wq = (const float*)d_in[1];
    const float* bq = (const float*)d_in[2];
    const float* Wk = (const float*)d_in[3];
    const float* bk = (const float*)d_in[4];
    const float* Wv = (const float*)d_in[5];
    const float* bv = (const float*)d_in[6];
    const float* Wo = (const float*)d_in[7];
    const float* bo = (const float*)d_in[8];
    float* out = (float*)d_out;

    // ws (32 MB, proven): [xb | q | k | v] bf16; attn output aliases xb.
    bf16* xb  = (bf16*)d_ws;
    bf16* qws = xb  + 4194304;
    bf16* kws = qws + 4194304;
    bf16* vws = kws + 4194304;
    bf16* aws = xb;

    // d_out scratch: bf16 Wq|Wk|Wv (6 MB); dead before out_gemm writes.
    bf16* wb = (bf16*)d_out;

    conv_all<<<dim3(3584), 256, 0, stream>>>(x, Wq, Wk, Wv, xb, wb);
    qkv_gemm<<<dim3(24, 32), 256, 0, stream>>>(xb, wb, bq, bk, bv, qws, kws, vws);
    attn_kernel<<<dim3(512), 256, 0, stream>>>(qws, kws, vws, aws);
    out_gemm<<<dim3(8, 32), 256, 0, stream>>>(aws, Wo, bo, out);
}

// Round 12
// 235.086 us; speedup vs baseline: 1.1212x; 1.0386x over previous
//
#include <hip/hip_runtime.h>
#include <hip/hip_bf16.h>

typedef __bf16 bf16;
typedef __bf16 bf16x8 __attribute__((ext_vector_type(8)));
typedef float  f32x4  __attribute__((ext_vector_type(4)));

#define NEG_BIG (-1e30f)

#define AS1(p) ((const __attribute__((address_space(1))) void*)(p))
#define AS3(p) ((__attribute__((address_space(3))) void*)(p))

// async global->LDS, 16B/lane; dest = wave-uniform base + lane*16 (m104/m108)
__device__ __forceinline__ void stage16(const void* g, void* lds_uniform_base) {
    __builtin_amdgcn_global_load_lds(AS1(g), AS3(lds_uniform_base), 16, 0, 0);
}

__device__ __forceinline__ bf16x8 cvt8(const float* __restrict__ p) {
    bf16x8 r;
#pragma unroll
    for (int i = 0; i < 8; ++i) r[i] = (bf16)p[i];
    return r;
}

// ---------------------------------------------------------------------------
// f32->bf16: x -> xb (ws), Wq/Wk/Wv -> wb (d_out scratch). (R7-proven.)
// ---------------------------------------------------------------------------
__global__ __launch_bounds__(256) void conv_all(
    const float* __restrict__ x,  const float* __restrict__ wq,
    const float* __restrict__ wk, const float* __restrict__ wv,
    bf16* __restrict__ xb, bf16* __restrict__ wb)
{
    const int blk = blockIdx.x;
    const float* src; bf16* dst; size_t off;
    if (blk < 2048)      { src = x;  dst = xb;           off = (size_t)blk * 2048; }
    else if (blk < 2560) { src = wq; dst = wb;           off = (size_t)(blk - 2048) * 2048; }
    else if (blk < 3072) { src = wk; dst = wb + 1048576; off = (size_t)(blk - 2560) * 2048; }
    else                 { src = wv; dst = wb + 2097152; off = (size_t)(blk - 3072) * 2048; }
    const size_t i = off + (size_t)threadIdx.x * 8;
    *(bf16x8*)(dst + i) = cvt8(src + i);
}

// ---------------------------------------------------------------------------
// Fused QKV projection, all-bf16 (R7-proven). y = xb @ Wb.T + b.
// ---------------------------------------------------------------------------
__global__ __launch_bounds__(256) void qkv_gemm(
    const bf16* __restrict__ Xb, const bf16* __restrict__ Wb,
    const float* __restrict__ bq, const float* __restrict__ bk, const float* __restrict__ bv,
    bf16* __restrict__ qo, bf16* __restrict__ ko, bf16* __restrict__ vo)
{
    __shared__ alignas(16) bf16 As[128 * 32];
    __shared__ alignas(16) bf16 Bs[128 * 32];

    const int t    = threadIdx.x;
    const int lane = t & 63, w = t >> 6;
    const int quad = lane >> 4, col = lane & 15;
    const int nt = blockIdx.x;            // 0..23
    const int mt = blockIdx.y;            // 0..31
    const int region = nt >> 3;           // 0=q 1=k 2=v
    const int n0 = (nt & 7) * 128;
    const int m0 = mt * 128;
    const int K  = 1024;

    const bf16*  W    = Wb + (size_t)region * 1048576;
    const float* bias = region == 0 ? bq : (region == 1 ? bk : bv);
    bf16*        out  = region == 0 ? qo : (region == 1 ? ko : vo);
    const float scale = region == 0 ? 0.125f : 1.0f;

    const int wm = (w >> 1) * 64, wn = (w & 1) * 64;
    f32x4 acc[4][4] = {};

    for (int k0 = 0; k0 < K; k0 += 32) {
        __syncthreads();
#pragma unroll
        for (int i = 0; i < 2; ++i) {
            int c = i * 256 + t;
            stage16(Xb + (size_t)(m0 + (c >> 2)) * K + k0 + (c & 3) * 8,
                    As + (i * 256 + w * 64) * 8);
        }
#pragma unroll
        for (int i = 0; i < 2; ++i) {
            int c = i * 256 + t;
            stage16(W + (size_t)(n0 + (c >> 2)) * K + k0 + (c & 3) * 8,
                    Bs + (i * 256 + w * 64) * 8);
        }
        __syncthreads();

        bf16x8 a[4], b[4];
#pragma unroll
        for (int i = 0; i < 4; ++i)
            a[i] = *(const bf16x8*)(As + (wm + i * 16 + col) * 32 + quad * 8);
#pragma unroll
        for (int j = 0; j < 4; ++j)
            b[j] = *(const bf16x8*)(Bs + (wn + j * 16 + col) * 32 + quad * 8);
#pragma unroll
        for (int i = 0; i < 4; ++i)
#pragma unroll
            for (int j = 0; j < 4; ++j)
                acc[i][j] = __builtin_amdgcn_mfma_f32_16x16x32_bf16(a[i], b[j], acc[i][j], 0, 0, 0);
    }

#pragma unroll
    for (int i = 0; i < 4; ++i) {
        const int mbase = m0 + wm + i * 16 + quad * 4;
#pragma unroll
        for (int j = 0; j < 4; ++j) {
            const int n = n0 + wn + j * 16 + col;
            const float bb = bias[n];
            const int h = n >> 6, d = n & 63;
#pragma unroll
            for (int r = 0; r < 4; ++r) {
                const int m  = mbase + r;
                const int b_ = m >> 11, s = m & 2047;
                out[(((size_t)(b_ * 16 + h)) * 2048 + s) * 64 + d] =
                    (bf16)((acc[i][j][r] + bb) * scale);
            }
        }
    }
}

// ---------------------------------------------------------------------------
// Flash attention — R7-proven inner machinery, EQUAL-WORK blocks:
// grid = 8 pairs x 32 bh = 256 blocks; each block runs q-tile (15-pair) then
// q-tile (pair). Work per block = (16-pair)+(pair+1) = 17 kv-stagings for
// EVERY block -> zero tail, no dispatch-order assumptions.
// ---------------------------------------------------------------------------
__global__ __launch_bounds__(256) void attn_kernel(
    const bf16* __restrict__ Q, const bf16* __restrict__ Kg,
    const bf16* __restrict__ Vg, bf16* __restrict__ O)
{
    const int t    = threadIdx.x;
    const int lane = t & 63, w = t >> 6;
    const int quad = lane >> 4, col = lane & 15;
    const int bh   = blockIdx.x & 31;
    const int pair = blockIdx.x >> 5;         // 0..7
    const int b  = bh >> 4, h = bh & 15;
    const float nslope = -exp2f(-0.5f * (float)(h + 1));

    const bf16* qp = Q  + (size_t)bh * 2048 * 64;
    const bf16* kp = Kg + (size_t)bh * 2048 * 64;
    const bf16* vp = Vg + (size_t)bh * 2048 * 64;

    __shared__ alignas(16) bf16 KP[4 * 32 * 136];   // Ks (9216) ∪ Ps (17408)
    __shared__ alignas(16) bf16 Vt[64 * 136];
    bf16* Ks = KP;
    bf16* Pw = KP + w * (32 * 136);

    for (int pass = 0; pass < 2; ++pass) {
        const int qt = pass == 0 ? (15 - pair) : pair;
        const int q0 = qt * 128;

        bf16x8 qa[2][2];
#pragma unroll
        for (int mi = 0; mi < 2; ++mi)
#pragma unroll
            for (int ks = 0; ks < 2; ++ks)
                qa[mi][ks] = *(const bf16x8*)(qp + (size_t)(q0 + w * 32 + mi * 16 + col) * 64
                                              + ks * 32 + quad * 8);

        float mrow[2][4], lrow[2][4];
        f32x4 of[2][4] = {};
#pragma unroll
        for (int mi = 0; mi < 2; ++mi)
#pragma unroll
            for (int r = 0; r < 4; ++r) { mrow[mi][r] = NEG_BIG; lrow[mi][r] = 0.f; }

        for (int kvt = 0; kvt <= qt; ++kvt) {
            const int kv0 = kvt * 128;

            bf16x8 kx[4], va[2], vb_[2];
#pragma unroll
            for (int i = 0; i < 4; ++i) {
                int c = i * 256 + t;
                kx[i] = *(const bf16x8*)(kp + (size_t)(kv0 + (c >> 3)) * 64 + (c & 7) * 8);
            }
#pragma unroll
            for (int i = 0; i < 2; ++i) {
                int c = i * 256 + t;
                va[i]  = *(const bf16x8*)(vp + (size_t)(kv0 + (c >> 3) * 2)     * 64 + (c & 7) * 8);
                vb_[i] = *(const bf16x8*)(vp + (size_t)(kv0 + (c >> 3) * 2 + 1) * 64 + (c & 7) * 8);
            }
            __syncthreads();   // BARRIER1: all waves done with prev KP(Pw)/Vt reads
#pragma unroll
            for (int i = 0; i < 4; ++i) {
                int c = i * 256 + t;
                *(bf16x8*)(Ks + (c >> 3) * 72 + (c & 7) * 8) = kx[i];
            }
#pragma unroll
            for (int i = 0; i < 2; ++i) {
                int c = i * 256 + t;
                int kvp = c >> 3, dc = (c & 7) * 8;
#pragma unroll
                for (int e = 0; e < 8; ++e) {
                    Vt[(dc + e) * 136 + kvp * 2]     = va[i][e];
                    Vt[(dc + e) * 136 + kvp * 2 + 1] = vb_[i][e];
                }
            }
            __syncthreads();   // BARRIER2: Ks/Vt visible

            // S = Q K^T
            f32x4 sc[2][8];
#pragma unroll
            for (int nj = 0; nj < 8; ++nj) {
                bf16x8 k0f = *(const bf16x8*)(Ks + (nj * 16 + col) * 72 + quad * 8);
                bf16x8 k1f = *(const bf16x8*)(Ks + (nj * 16 + col) * 72 + 32 + quad * 8);
#pragma unroll
                for (int mi = 0; mi < 2; ++mi) {
                    f32x4 z = {};
                    z = __builtin_amdgcn_mfma_f32_16x16x32_bf16(qa[mi][0], k0f, z, 0, 0, 0);
                    z = __builtin_amdgcn_mfma_f32_16x16x32_bf16(qa[mi][1], k1f, z, 0, 0, 0);
                    sc[mi][nj] = z;
                }
            }

            const bool diag = (kvt == qt);
#pragma unroll
            for (int mi = 0; mi < 2; ++mi) {
#pragma unroll
                for (int r = 0; r < 4; ++r) {
                    const int gi = q0 + w * 32 + mi * 16 + quad * 4 + r;
                    float mx = NEG_BIG;
#pragma unroll
                    for (int nj = 0; nj < 8; ++nj) {
                        const int gj = kv0 + nj * 16 + col;
                        float val = sc[mi][nj][r] + nslope * (float)(gi - gj);
                        if (diag && gj > gi) val = NEG_BIG;
                        sc[mi][nj][r] = val;
                        mx = fmaxf(mx, val);
                    }
#pragma unroll
                    for (int off = 1; off < 16; off <<= 1)
                        mx = fmaxf(mx, __shfl_xor(mx, off, 16));
                    const float mo = mrow[mi][r];
                    const float mn = fmaxf(mo, mx);
                    const float alpha = __expf(mo - mn);
                    float rs = 0.f;
#pragma unroll
                    for (int nj = 0; nj < 8; ++nj) {
                        float p = __expf(sc[mi][nj][r] - mn);
                        sc[mi][nj][r] = p;
                        rs += p;
                    }
#pragma unroll
                    for (int off = 1; off < 16; off <<= 1)
                        rs += __shfl_xor(rs, off, 16);
                    mrow[mi][r] = mn;
                    lrow[mi][r] = lrow[mi][r] * alpha + rs;
#pragma unroll
                    for (int jd = 0; jd < 4; ++jd) of[mi][jd][r] *= alpha;
                }
            }

            __syncthreads();   // BARRIER3: all waves done reading Ks before P overwrite

            // P: C/D -> A-operand layout via per-wave LDS region (aliases Ks)
#pragma unroll
            for (int mi = 0; mi < 2; ++mi)
#pragma unroll
                for (int nj = 0; nj < 8; ++nj)
#pragma unroll
                    for (int r = 0; r < 4; ++r)
                        Pw[(mi * 16 + quad * 4 + r) * 136 + nj * 16 + col] = (bf16)sc[mi][nj][r];

            // O += P V
#pragma unroll
            for (int kk = 0; kk < 4; ++kk) {
                bf16x8 pa0 = *(const bf16x8*)(Pw + (col)      * 136 + kk * 32 + quad * 8);
                bf16x8 pa1 = *(const bf16x8*)(Pw + (16 + col) * 136 + kk * 32 + quad * 8);
#pragma unroll
                for (int jd = 0; jd < 4; ++jd) {
                    bf16x8 vbf = *(const bf16x8*)(Vt + (jd * 16 + col) * 136 + kk * 32 + quad * 8);
                    of[0][jd] = __builtin_amdgcn_mfma_f32_16x16x32_bf16(pa0, vbf, of[0][jd], 0, 0, 0);
                    of[1][jd] = __builtin_amdgcn_mfma_f32_16x16x32_bf16(pa1, vbf, of[1][jd], 0, 0, 0);
                }
            }
        }

        // normalize + write this q-tile's attn output (bf16) to [B,S,E]
#pragma unroll
        for (int mi = 0; mi < 2; ++mi)
#pragma unroll
            for (int r = 0; r < 4; ++r) {
                const int s = q0 + w * 32 + mi * 16 + quad * 4 + r;
                const float inv_l = 1.f / lrow[mi][r];
#pragma unroll
                for (int jd = 0; jd < 4; ++jd) {
                    const int e = h * 64 + jd * 16 + col;
                    O[((size_t)(b * 2048 + s)) * 1024 + e] = (bf16)(of[mi][jd][r] * inv_l);
                }
            }
    }
}

// ---------------------------------------------------------------------------
// Output projection (R7-proven): A bf16 via stage16; Wo f32 via cvt8.
// ---------------------------------------------------------------------------
__global__ __launch_bounds__(256) void out_gemm(
    const bf16* __restrict__ A, const float* __restrict__ W,
    const float* __restrict__ bias, float* __restrict__ out)
{
    __shared__ alignas(16) bf16 As[128 * 32];
    __shared__ alignas(16) bf16 Bs[128 * 32];

    const int t    = threadIdx.x;
    const int lane = t & 63, w = t >> 6;
    const int quad = lane >> 4, col = lane & 15;
    const int n0 = blockIdx.x * 128;
    const int m0 = blockIdx.y * 128;
    const int K  = 1024;
    const int wm = (w >> 1) * 64, wn = (w & 1) * 64;
    const int r0 = t >> 2, c8 = (t & 3) * 8;
    f32x4 acc[4][4] = {};

    for (int k0 = 0; k0 < K; k0 += 32) {
        bf16x8 bx0 = cvt8(W + (size_t)(n0 + r0)      * K + k0 + c8);
        bf16x8 bx1 = cvt8(W + (size_t)(n0 + 64 + r0) * K + k0 + c8);
        __syncthreads();
#pragma unroll
        for (int i = 0; i < 2; ++i) {
            int c = i * 256 + t;
            stage16(A + (size_t)(m0 + (c >> 2)) * K + k0 + (c & 3) * 8,
                    As + (i * 256 + w * 64) * 8);
        }
        *(bf16x8*)(Bs + r0 * 32 + c8)        = bx0;
        *(bf16x8*)(Bs + (64 + r0) * 32 + c8) = bx1;
        __syncthreads();

        bf16x8 a[4], b[4];
#pragma unroll
        for (int i = 0; i < 4; ++i)
            a[i] = *(const bf16x8*)(As + (wm + i * 16 + col) * 32 + quad * 8);
#pragma unroll
        for (int j = 0; j < 4; ++j)
            b[j] = *(const bf16x8*)(Bs + (wn + j * 16 + col) * 32 + quad * 8);
#pragma unroll
        for (int i = 0; i < 4; ++i)
#pragma unroll
            for (int j = 0; j < 4; ++j)
                acc[i][j] = __builtin_amdgcn_mfma_f32_16x16x32_bf16(a[i], b[j], acc[i][j], 0, 0, 0);
    }

#pragma unroll
    for (int i = 0; i < 4; ++i) {
        const int mbase = m0 + wm + i * 16 + quad * 4;
#pragma unroll
        for (int j = 0; j < 4; ++j) {
            const int n = n0 + wn + j * 16 + col;
            const float bb = bias[n];
#pragma unroll
            for (int r = 0; r < 4; ++r)
                out[(size_t)(mbase + r) * 1024 + n] = acc[i][j][r] + bb;
        }
    }
}

extern "C" void kernel_launch(void* const* d_in, const int* in_sizes, int n_in,
                              void* d_out, int out_size, void* d_ws, size_t ws_size,
                              hipStream_t stream) {
    const float* x  = (const float*)d_in[0];
    const float* Wq = (const float*)d_in[1];
    const float* bq = (const float*)d_in[2];
    const float* Wk = (const float*)d_in[3];
    const float* bk = (const float*)d_in[4];
    const float* Wv = (const float*)d_in[5];
    const float* bv = (const float*)d_in[6];
    const float* Wo = (const float*)d_in[7];
    const float* bo = (const float*)d_in[8];
    float* out = (float*)d_out;

    // ws (32 MB, proven): [xb | q | k | v] bf16; attn output aliases xb.
    bf16* xb  = (bf16*)d_ws;
    bf16* qws = xb  + 4194304;
    bf16* kws = qws + 4194304;
    bf16* vws = kws + 4194304;
    bf16* aws = xb;

    // d_out scratch: bf16 Wq|Wk|Wv (6 MB); dead before out_gemm writes.
    bf16* wb = (bf16*)d_out;

    conv_all<<<dim3(3584), 256, 0, stream>>>(x, Wq, Wk, Wv, xb, wb);
    qkv_gemm<<<dim3(24, 32), 256, 0, stream>>>(xb, wb, bq, bk, bv, qws, kws, vws);
    attn_kernel<<<dim3(256), 256, 0, stream>>>(qws, kws, vws, aws);
    out_gemm<<<dim3(8, 32), 256, 0, stream>>>(aws, Wo, bo, out);
}